// Round 3
// baseline (23963.712 us; speedup 1.0000x reference)
//
#include <hip/hip_runtime.h>
#include <hip/hip_bf16.h>
#include <stdint.h>

#define HD   512   // hidden dim H
#define ID   128   // input dim I
#define NCLS 100   // num classes
#define TT   512   // sequence length T
#define BB   128   // batch B
#define NEMB 101   // NC + 1 embedding rows
#define RPW  2     // batch rows per workgroup

// workspace layout (bytes)
#define WS_G    4096           // float G[101][2048]          (808 KB)
#define WS_WCT  (1u << 20)     // WcT: bf16 mode 1.5 MB / f32 mode 3 MB

using bf16 = __hip_bfloat16;

__device__ __forceinline__ float b2f(bf16 v) { return __bfloat162float(v); }
__device__ __forceinline__ float sigf(float x) { return 1.0f / (1.0f + __expf(-x)); }
// unpack 2 bf16 (packed in a uint32, little-endian) to 2 f32 — exact
__device__ __forceinline__ float2 upk(unsigned int u) {
    float2 r;
    r.x = __uint_as_float(u << 16);
    r.y = __uint_as_float(u & 0xFFFF0000u);
    return r;
}

template <bool BF>
__device__ __forceinline__ float ldv(const void* p, int i) {
    if constexpr (BF) return b2f(((const bf16*)p)[i]);
    else              return ((const float*)p)[i];
}

// ---------------------------------------------------------------------------
// Dtype sniffer. emb row 0 is exactly 0.0 by construction. Bytes [256,512):
//   f32 -> still row 0 -> all zero ; bf16 -> row 1 (random normals) -> nonzero
// ---------------------------------------------------------------------------
__global__ void detect_mode(const uint32_t* __restrict__ emb_raw, int* __restrict__ flag) {
    if (threadIdx.x == 0) {
        uint32_t acc = 0;
        for (int i = 64; i < 128; ++i) acc |= emb_raw[i];
        *flag = (acc == 0u) ? 0 : 1;
    }
}

// ---------------------------------------------------------------------------
// G[c][j], c in [0,101), j in [0,2048): input-side gate pre-activations per
// class. j = q*512 + col, q in {0:f, 1:i, 2:o, 3:ctilde}; ctilde quarter is
// pre-sigmoided (never receives a cg contribution).
// ---------------------------------------------------------------------------
template <bool BF>
__global__ void build_G(const int* __restrict__ flag,
                        const void* __restrict__ emb,
                        const void* __restrict__ Wfx, const void* __restrict__ Wix,
                        const void* __restrict__ Wox, const void* __restrict__ Wcx,
                        const void* __restrict__ bfv, const void* __restrict__ biv,
                        const void* __restrict__ bov, const void* __restrict__ bcv,
                        float* __restrict__ G) {
    if (*flag != (BF ? 1 : 0)) return;
    const int c   = blockIdx.x;
    const int j   = blockIdx.y * 256 + threadIdx.x;
    const int q   = j >> 9;
    const int col = j & 511;
    const void* W  = (q == 0) ? Wfx : (q == 1) ? Wix : (q == 2) ? Wox : Wcx;
    const void* bv = (q == 0) ? bfv : (q == 1) ? biv : (q == 2) ? bov : bcv;
    float acc = ldv<BF>(bv, col);
    for (int i = 0; i < ID; ++i)
        acc += ldv<BF>(emb, c * ID + i) * ldv<BF>(W, i * HD + col);
    if (q == 3) acc = sigf(acc);
    G[c * 2048 + j] = acc;
}

// ---------------------------------------------------------------------------
// WcT[j][h] = Wc[h][j]: rows 0..511 = f cols, 512..1023 = i cols,
// 1024..1535 = o cols. Row j contiguous (512 elems) for per-thread streaming.
// Hot per-step slab = rows [0,1024) = 2 MB f32 / 1 MB bf16 -> L2-resident.
// ---------------------------------------------------------------------------
template <bool BF>
__global__ void build_WcT(const int* __restrict__ flag,
                          const void* __restrict__ Wfc, const void* __restrict__ Wic,
                          const void* __restrict__ Woc, void* __restrict__ WcT) {
    if (*flag != (BF ? 1 : 0)) return;
    const int gid = blockIdx.x * 256 + threadIdx.x; // < 1536*512
    const int j = gid >> 9;
    const int h = gid & 511;
    const void* W = (j < 512) ? Wfc : (j < 1024) ? Wic : Woc;
    const int jj = j & 511;
    const float v = ldv<BF>(W, h * HD + jj);
    if constexpr (BF) ((bf16*)WcT)[(size_t)j * HD + h] = __float2bfloat16(v);
    else              ((float*)WcT)[(size_t)j * HD + h] = v;
}

// ---------------------------------------------------------------------------
// One WG per 2 batch rows, 1024 threads. Threads 0..511 own f-col jj (and the
// C update for col jj, both rows); threads 512..1023 own i-col jj (and o-col
// jj at the final step). C in LDS (wave-uniform broadcast reads) + f-threads
// keep their own C element in registers. Reset multiplier applied per step.
// ---------------------------------------------------------------------------
template <bool BF>
__global__ __launch_bounds__(1024) void recur(
    const int*  __restrict__ flag, const int*  __restrict__ x,
    const float* __restrict__ G,   const void* __restrict__ WcT,
    const void* __restrict__ Wph,  const void* __restrict__ bp,
    void* __restrict__ out)
{
    if (*flag != (BF ? 1 : 0)) return;

    __shared__ __align__(16) float C_s [RPW][HD];
    __shared__ __align__(16) float ii_s[RPW][HD];
    __shared__ __align__(16) float o_s [RPW][HD];
    __shared__ float h_s[RPW][HD];
    __shared__ int   idx_s[RPW][TT];
    __shared__ float p_s[RPW][NCLS];
    __shared__ float lse_s[RPW];
    __shared__ int   lastz[RPW];

    const int b0  = blockIdx.x * RPW;
    const int tid = threadIdx.x;          // 0..1023
    const bool isF = (tid < HD);
    const int jj  = tid & (HD - 1);
    const int r   = tid >> 9;             // 0 or 1 (for per-row chores)

    idx_s[r][jj] = x[(b0 + r) * TT + jj];
    if (tid < RPW) lastz[tid] = -1;
    C_s[r][jj] = 0.0f;
    h_s[r][jj] = 0.0f;
    __syncthreads();
    if (idx_s[r][jj] == 0) atomicMax(&lastz[r], jj);
    __syncthreads();
    const int tstart = min(lastz[0], lastz[1]) + 1;  // reset mult keeps rows exact

    const float4* C40 = reinterpret_cast<const float4*>(C_s[0]);
    const float4* C41 = reinterpret_cast<const float4*>(C_s[1]);

    float Creg0 = 0.0f, Creg1 = 0.0f;     // f-threads: own C element per row

    // per-thread weight stream base: row `tid` (f: 0..511, i: 512..1023)
    const uint4*  wB = nullptr; const uint4*  wBo = nullptr;
    const float4* wF = nullptr; const float4* wFo = nullptr;
    if constexpr (BF) {
        const bf16* W = (const bf16*)WcT;
        wB  = reinterpret_cast<const uint4*>(W + (size_t)tid * HD);
        wBo = reinterpret_cast<const uint4*>(W + (size_t)(2 * HD + jj) * HD);
    } else {
        const float* W = (const float*)WcT;
        wF  = reinterpret_cast<const float4*>(W + (size_t)tid * HD);
        wFo = reinterpret_cast<const float4*>(W + (size_t)(2 * HD + jj) * HD);
    }

    for (int t = tstart; t < TT; ++t) {
        const int cA = idx_s[0][t];
        const int cB = idx_s[1][t];
        const bool last = (t == TT - 1);
        const float* GA = G + cA * 2048;
        const float* GB = G + cB * 2048;

        // issue this step's G loads early (overlap with the dot latency)
        const float gA = isF ? GA[jj] : GA[HD + jj];
        const float gB = isF ? GB[jj] : GB[HD + jj];
        float sgcA = 0.f, sgcB = 0.f;
        if (isF) { sgcA = GA[3 * HD + jj]; sgcB = GB[3 * HD + jj]; }

        float a0 = 0.0f, a1 = 0.0f;       // own-col dot vs C row0 / row1
        if constexpr (BF) {
            #pragma unroll 8
            for (int hh = 0; hh < HD / 8; ++hh) {
                const uint4 u = wB[hh];
                const float4 cA0 = C40[2 * hh], cA1 = C40[2 * hh + 1];
                const float4 cB0 = C41[2 * hh], cB1 = C41[2 * hh + 1];
                float2 p;
                p = upk(u.x); a0 += cA0.x * p.x + cA0.y * p.y; a1 += cB0.x * p.x + cB0.y * p.y;
                p = upk(u.y); a0 += cA0.z * p.x + cA0.w * p.y; a1 += cB0.z * p.x + cB0.w * p.y;
                p = upk(u.z); a0 += cA1.x * p.x + cA1.y * p.y; a1 += cB1.x * p.x + cB1.y * p.y;
                p = upk(u.w); a0 += cA1.z * p.x + cA1.w * p.y; a1 += cB1.z * p.x + cB1.w * p.y;
            }
        } else {
            #pragma unroll 8
            for (int hh = 0; hh < HD / 4; ++hh) {
                const float4 w  = wF[hh];
                const float4 c0 = C40[hh];
                const float4 c1 = C41[hh];
                a0 += w.x * c0.x + w.y * c0.y + w.z * c0.z + w.w * c0.w;
                a1 += w.x * c1.x + w.y * c1.y + w.z * c1.z + w.w * c1.w;
            }
        }

        if (!isF) {
            ii_s[0][jj] = sigf(gA + a0);
            ii_s[1][jj] = sigf(gB + a1);
            if (last) {                    // o-gate needed only for h[T-1]
                float b0a = 0.0f, b1a = 0.0f;
                if constexpr (BF) {
                    #pragma unroll 8
                    for (int hh = 0; hh < HD / 8; ++hh) {
                        const uint4 u = wBo[hh];
                        const float4 cA0 = C40[2 * hh], cA1 = C40[2 * hh + 1];
                        const float4 cB0 = C41[2 * hh], cB1 = C41[2 * hh + 1];
                        float2 p;
                        p = upk(u.x); b0a += cA0.x * p.x + cA0.y * p.y; b1a += cB0.x * p.x + cB0.y * p.y;
                        p = upk(u.y); b0a += cA0.z * p.x + cA0.w * p.y; b1a += cB0.z * p.x + cB0.w * p.y;
                        p = upk(u.z); b0a += cA1.x * p.x + cA1.y * p.y; b1a += cB1.x * p.x + cB1.y * p.y;
                        p = upk(u.w); b0a += cA1.z * p.x + cA1.w * p.y; b1a += cB1.z * p.x + cB1.w * p.y;
                    }
                } else {
                    #pragma unroll 8
                    for (int hh = 0; hh < HD / 4; ++hh) {
                        const float4 w  = wFo[hh];
                        const float4 c0 = C40[hh];
                        const float4 c1 = C41[hh];
                        b0a += w.x * c0.x + w.y * c0.y + w.z * c0.z + w.w * c0.w;
                        b1a += w.x * c1.x + w.y * c1.y + w.z * c1.z + w.w * c1.w;
                    }
                }
                o_s[0][jj] = sigf(GA[2 * HD + jj] + b0a);
                o_s[1][jj] = sigf(GB[2 * HD + jj] + b1a);
            }
        }
        __syncthreads();                   // ii (and o) ready; all C reads done
        if (isF) {
            const float f0 = sigf(gA + a0);
            const float f1 = sigf(gB + a1);
            const float rm0 = (cA > 0) ? 1.0f : 0.0f;
            const float rm1 = (cB > 0) ? 1.0f : 0.0f;
            Creg0 = (sgcA * ii_s[0][jj] + Creg0 * f0) * rm0;
            Creg1 = (sgcB * ii_s[1][jj] + Creg1 * f1) * rm1;
            C_s[0][jj] = Creg0;
            C_s[1][jj] = Creg1;
            if (last) {
                h_s[0][jj] = tanhf(Creg0) * o_s[0][jj];
                h_s[1][jj] = tanhf(Creg1) * o_s[1][jj];
            }
        }
        __syncthreads();                   // C updated before next step's dots
    }

    // ---- projection + log_softmax, both rows in parallel ----
    if (jj < NCLS) {
        float p = ldv<BF>(bp, jj);
        for (int hh = 0; hh < HD; ++hh)
            p += h_s[r][hh] * ldv<BF>(Wph, hh * NCLS + jj);
        p_s[r][jj] = p;
    }
    __syncthreads();
    if (jj == 0) {
        float m = -1e30f;
        for (int n = 0; n < NCLS; ++n) m = fmaxf(m, p_s[r][n]);
        float s = 0.0f;
        for (int n = 0; n < NCLS; ++n) s += __expf(p_s[r][n] - m);
        lse_s[r] = m + __logf(s);
    }
    __syncthreads();
    if (jj < NCLS) {
        const float v = p_s[r][jj] - lse_s[r];
        if constexpr (BF) ((bf16*)out)[(b0 + r) * NCLS + jj] = __float2bfloat16(v);
        else              ((float*)out)[(b0 + r) * NCLS + jj] = v;
    }
}

// ---------------------------------------------------------------------------
extern "C" void kernel_launch(void* const* d_in, const int* in_sizes, int n_in,
                              void* d_out, int out_size, void* d_ws, size_t ws_size,
                              hipStream_t stream) {
    const int* x   = (const int*)d_in[0];
    const void* emb = d_in[1];
    const void* Wfx = d_in[2];
    const void* Wfc = d_in[3];
    const void* bfv = d_in[4];
    const void* Wix = d_in[5];
    const void* Wic = d_in[6];
    const void* biv = d_in[7];
    const void* Wox = d_in[8];
    const void* Woc = d_in[9];
    const void* bov = d_in[10];
    const void* Wcx = d_in[11];
    const void* bcv = d_in[12];
    const void* Wph = d_in[13];
    const void* bp  = d_in[14];

    int*   flag = (int*)d_ws;
    float* G    = (float*)((char*)d_ws + WS_G);
    void*  WcT  = (void*)((char*)d_ws + WS_WCT);

    detect_mode<<<1, 64, 0, stream>>>((const uint32_t*)emb, flag);

    build_G<false><<<dim3(NEMB, 8), 256, 0, stream>>>(flag, emb, Wfx, Wix, Wox, Wcx,
                                                      bfv, biv, bov, bcv, G);
    build_G<true ><<<dim3(NEMB, 8), 256, 0, stream>>>(flag, emb, Wfx, Wix, Wox, Wcx,
                                                      bfv, biv, bov, bcv, G);

    build_WcT<false><<<dim3((1536 * 512) / 256), 256, 0, stream>>>(flag, Wfc, Wic, Woc, WcT);
    build_WcT<true ><<<dim3((1536 * 512) / 256), 256, 0, stream>>>(flag, Wfc, Wic, Woc, WcT);

    recur<false><<<BB / RPW, RPW * HD, 0, stream>>>(flag, x, G, WcT, Wph, bp, d_out);
    recur<true ><<<BB / RPW, RPW * HD, 0, stream>>>(flag, x, G, WcT, Wph, bp, d_out);
}

// Round 4
// 16760.860 us; speedup vs baseline: 1.4297x; 1.4297x over previous
//
#include <hip/hip_runtime.h>
#include <hip/hip_bf16.h>
#include <hip/hip_cooperative_groups.h>
#include <stdint.h>

namespace cg = cooperative_groups;

#define HD   512   // hidden dim H
#define ID   128   // input dim I
#define NCLS 100   // num classes
#define TT   512   // sequence length T
#define BB   128   // batch B
#define NEMB 101   // NC + 1 embedding rows
#define NWG  256   // workgroups in the cooperative recurrence
#define HS   2     // hidden columns per WG (NWG*HS == HD)

// workspace layout (bytes)
#define WS_FLAG   0
#define WS_TSTART 8
#define WS_G      4096                     // float G[101][2048]  (808 KB)
#define WS_CT0    (1u * 1024 * 1024)       // float Ct0[512][128] (256 KB)
#define WS_CT1    (WS_CT0 + 262144)        // float Ct1[512][128] (256 KB)
#define WS_HFB    (WS_CT1 + 262144)        // float Hfb[128][512] (256 KB)

using bf16 = __hip_bfloat16;

__device__ __forceinline__ float b2f(bf16 v) { return __bfloat162float(v); }
__device__ __forceinline__ float sigf(float x) { return 1.0f / (1.0f + __expf(-x)); }

template <bool BF>
__device__ __forceinline__ float ldv(const void* p, int i) {
    if constexpr (BF) return b2f(((const bf16*)p)[i]);
    else              return ((const float*)p)[i];
}

// ---------------------------------------------------------------------------
// Dtype sniffer. emb row 0 is exactly 0.0 by construction. Bytes [256,512):
//   f32 -> still row 0 -> all zero ; bf16 -> row 1 (random normals) -> nonzero
// ---------------------------------------------------------------------------
__global__ void detect_mode(const uint32_t* __restrict__ emb_raw, int* __restrict__ flag) {
    if (threadIdx.x == 0) {
        uint32_t acc = 0;
        for (int i = 64; i < 128; ++i) acc |= emb_raw[i];
        *flag = (acc == 0u) ? 0 : 1;
    }
}

// ---------------------------------------------------------------------------
// Global start step: t0 = min_b(last zero position) + 1. Rows whose last
// reset is later than t0 get garbage C until their reset zeroes it — harmless
// since C is only consumed through the post-reset suffix and h only at T-1.
// ---------------------------------------------------------------------------
__global__ void scan_tstart(const int* __restrict__ x, int* __restrict__ tstart) {
    __shared__ int lz_s[BB];
    const int b = threadIdx.x;           // 128 threads
    int lz = -1;
    for (int t = 0; t < TT; ++t)
        if (x[b * TT + t] == 0) lz = t;
    lz_s[b] = lz;
    __syncthreads();
    if (b == 0) {
        int m = lz_s[0];
        for (int i = 1; i < BB; ++i) m = min(m, lz_s[i]);
        *tstart = m + 1;
    }
}

// ---------------------------------------------------------------------------
// G[c][j], c in [0,101), j in [0,2048): input-side gate pre-activations per
// class. j = q*512 + col, q in {0:f, 1:i, 2:o, 3:ctilde}; ctilde quarter is
// pre-sigmoided (never receives a cg contribution).
// ---------------------------------------------------------------------------
template <bool BF>
__global__ void build_G(const int* __restrict__ flag,
                        const void* __restrict__ emb,
                        const void* __restrict__ Wfx, const void* __restrict__ Wix,
                        const void* __restrict__ Wox, const void* __restrict__ Wcx,
                        const void* __restrict__ bfv, const void* __restrict__ biv,
                        const void* __restrict__ bov, const void* __restrict__ bcv,
                        float* __restrict__ G) {
    if (*flag != (BF ? 1 : 0)) return;
    const int c   = blockIdx.x;
    const int j   = blockIdx.y * 256 + threadIdx.x;
    const int q   = j >> 9;
    const int col = j & 511;
    const void* W  = (q == 0) ? Wfx : (q == 1) ? Wix : (q == 2) ? Wox : Wcx;
    const void* bv = (q == 0) ? bfv : (q == 1) ? biv : (q == 2) ? bov : bcv;
    float acc = ldv<BF>(bv, col);
    for (int i = 0; i < ID; ++i)
        acc += ldv<BF>(emb, c * ID + i) * ldv<BF>(W, i * HD + col);
    if (q == 3) acc = sigf(acc);
    G[c * 2048 + j] = acc;
}

// ---------------------------------------------------------------------------
// Cooperative column-parallel recurrence. WG g owns hidden cols h0=2g..2g+1.
// Weights for its 2 f-cols, 2 i-cols, 2 o-cols live in LDS (12 KB) for the
// whole kernel -> zero per-step weight traffic. Per step each WG streams the
// 256 KB C-state (Ct[h'][b], f32, double-buffered in ws) and computes cg for
// its cols over ALL 128 batch rows, then updates C for its cols. grid.sync()
// per step. Thread map: tid = q(32) + 32*c(4) + 128*s(4); q = batch quad,
// c = {f0,f1,i0,i1}, s = quarter of the h' reduction.
// ---------------------------------------------------------------------------
template <bool BF>
__global__ __launch_bounds__(512) void recur_cp(
    const int* __restrict__ flag, const int* __restrict__ tstart,
    const int* __restrict__ x,    const float* __restrict__ G,
    const void* __restrict__ Wfc, const void* __restrict__ Wic,
    const void* __restrict__ Woc,
    float* __restrict__ Ct0, float* __restrict__ Ct1,
    float* __restrict__ Hfb)
{
    if (*flag != (BF ? 1 : 0)) return;
    cg::grid_group grid = cg::this_grid();

    __shared__ __align__(16) float  Wlds[6][HD];    // f0,f1,i0,i1,o0,o1 (12 KB)
    __shared__ __align__(16) float4 part4[4][4][32];// [s][c][q] partial dots (8 KB)
    __shared__ __align__(16) float4 dots4[4][32];   // [c][q] summed dots   (2 KB)

    const int g   = blockIdx.x;        // 0..255
    const int h0  = g * HS;
    const int tid = threadIdx.x;
    const int q   = tid & 31;
    const int c   = (tid >> 5) & 3;
    const int s   = tid >> 7;

    // ---- stage weights into LDS (one-time; strided gather is fine) ----
    for (int e = tid; e < 6 * HD; e += 512) {
        const int r  = e >> 9;          // 0..5
        const int hp = e & (HD - 1);
        const void* W = (r < 2) ? Wfc : (r < 4) ? Wic : Woc;
        Wlds[r][hp] = ldv<BF>(W, hp * HD + h0 + (r & 1));
    }
    // ---- zero-init both C buffers for our rows ----
    if (tid < HS * BB) {
        const int h = h0 + (tid >> 7);
        const int b = tid & (BB - 1);
        Ct0[h * BB + b] = 0.0f;
        Ct1[h * BB + b] = 0.0f;
    }
    grid.sync();

    const int t0 = *tstart;

    for (int t = t0; t < TT; ++t) {
        const float* cur = (t & 1) ? Ct1 : Ct0;
        float*       nxt = (t & 1) ? Ct0 : Ct1;
        const float4* cur4 = reinterpret_cast<const float4*>(cur);

        // ---- partial dot over our h' quarter, 4 batch rows per thread ----
        float a0 = 0.f, a1 = 0.f, a2 = 0.f, a3 = 0.f;
        const float* wrow = Wlds[c];
        const int base = s * 128;
        #pragma unroll 8
        for (int k = 0; k < 128; ++k) {
            const int hp = base + k;
            const float4 cv = cur4[hp * 32 + q];
            const float  w  = wrow[hp];
            a0 += w * cv.x; a1 += w * cv.y; a2 += w * cv.z; a3 += w * cv.w;
        }
        part4[s][c][q] = make_float4(a0, a1, a2, a3);
        __syncthreads();

        if (s == 0) {
            const float4 p0 = part4[0][c][q], p1 = part4[1][c][q];
            const float4 p2 = part4[2][c][q], p3 = part4[3][c][q];
            dots4[c][q] = make_float4(p0.x + p1.x + p2.x + p3.x,
                                      p0.y + p1.y + p2.y + p3.y,
                                      p0.z + p1.z + p2.z + p3.z,
                                      p0.w + p1.w + p2.w + p3.w);
        }
        __syncthreads();

        // ---- C update: threads (s==0, c<2) own col h0+c for 4 rows ----
        if (s == 0 && c < HS) {
            const int h  = h0 + c;
            const int b0 = q * 4;
            const float4 df   = dots4[c][q];
            const float4 di   = dots4[c + 2][q];
            const float4 cold = cur4[h * 32 + q];
            const int cl0 = x[(b0 + 0) * TT + t];
            const int cl1 = x[(b0 + 1) * TT + t];
            const int cl2 = x[(b0 + 2) * TT + t];
            const int cl3 = x[(b0 + 3) * TT + t];
            const float* G0 = G + cl0 * 2048;
            const float* G1 = G + cl1 * 2048;
            const float* G2 = G + cl2 * 2048;
            const float* G3 = G + cl3 * 2048;
            float4 cn;
            cn.x = (cl0 > 0) ? (G0[1536 + h] * sigf(G0[512 + h] + di.x) + cold.x * sigf(G0[h] + df.x)) : 0.0f;
            cn.y = (cl1 > 0) ? (G1[1536 + h] * sigf(G1[512 + h] + di.y) + cold.y * sigf(G1[h] + df.y)) : 0.0f;
            cn.z = (cl2 > 0) ? (G2[1536 + h] * sigf(G2[512 + h] + di.z) + cold.z * sigf(G2[h] + df.z)) : 0.0f;
            cn.w = (cl3 > 0) ? (G3[1536 + h] * sigf(G3[512 + h] + di.w) + cold.w * sigf(G3[h] + df.w)) : 0.0f;
            reinterpret_cast<float4*>(nxt)[h * 32 + q] = cn;
        }
        grid.sync();
    }

    // ---- o-gate + h only at the end (h is dead state mid-sequence) ----
    const float4* fin4 = reinterpret_cast<const float4*>((TT & 1) ? Ct1 : Ct0);
    {
        // 8-way split: col = c&1, chunk = s*2 + (c>>1) (64 h' each)
        float a0 = 0.f, a1 = 0.f, a2 = 0.f, a3 = 0.f;
        const float* wrow = Wlds[4 + (c & 1)];
        const int base = (s * 2 + (c >> 1)) * 64;
        #pragma unroll 8
        for (int k = 0; k < 64; ++k) {
            const int hp = base + k;
            const float4 cv = fin4[hp * 32 + q];
            const float  w  = wrow[hp];
            a0 += w * cv.x; a1 += w * cv.y; a2 += w * cv.z; a3 += w * cv.w;
        }
        part4[s][c][q] = make_float4(a0, a1, a2, a3);
        __syncthreads();
        if (s == 0 && c < HS) {
            float4 dO = make_float4(0.f, 0.f, 0.f, 0.f);
            #pragma unroll
            for (int sp = 0; sp < 4; ++sp) {
                const float4 pa = part4[sp][c][q];
                const float4 pb = part4[sp][c + 2][q];
                dO.x += pa.x + pb.x; dO.y += pa.y + pb.y;
                dO.z += pa.z + pb.z; dO.w += pa.w + pb.w;
            }
            const int h  = h0 + c;
            const int b0 = q * 4;
            const float4 cf = fin4[h * 32 + q];
            const int cl0 = x[(b0 + 0) * TT + TT - 1];
            const int cl1 = x[(b0 + 1) * TT + TT - 1];
            const int cl2 = x[(b0 + 2) * TT + TT - 1];
            const int cl3 = x[(b0 + 3) * TT + TT - 1];
            Hfb[(b0 + 0) * HD + h] = tanhf(cf.x) * sigf(G[cl0 * 2048 + 1024 + h] + dO.x);
            Hfb[(b0 + 1) * HD + h] = tanhf(cf.y) * sigf(G[cl1 * 2048 + 1024 + h] + dO.y);
            Hfb[(b0 + 2) * HD + h] = tanhf(cf.z) * sigf(G[cl2 * 2048 + 1024 + h] + dO.z);
            Hfb[(b0 + 3) * HD + h] = tanhf(cf.w) * sigf(G[cl3 * 2048 + 1024 + h] + dO.w);
        }
    }
}

// ---------------------------------------------------------------------------
// Projection + log_softmax. WG b: stage h row, dot vs Wph, normalize.
// ---------------------------------------------------------------------------
template <bool BF>
__global__ __launch_bounds__(128) void proj(
    const int* __restrict__ flag, const float* __restrict__ Hfb,
    const void* __restrict__ Wph, const void* __restrict__ bp,
    void* __restrict__ out)
{
    if (*flag != (BF ? 1 : 0)) return;
    __shared__ __align__(16) float hv[HD];
    __shared__ float p_s[NCLS];
    __shared__ float lse_s;
    const int b   = blockIdx.x;
    const int tid = threadIdx.x;

    reinterpret_cast<float4*>(hv)[tid] =
        reinterpret_cast<const float4*>(Hfb + b * HD)[tid];
    __syncthreads();

    if (tid < NCLS) {
        float p = ldv<BF>(bp, tid);
        for (int h = 0; h < HD; ++h)
            p += hv[h] * ldv<BF>(Wph, h * NCLS + tid);
        p_s[tid] = p;
    }
    __syncthreads();
    if (tid == 0) {
        float m = -1e30f;
        for (int n = 0; n < NCLS; ++n) m = fmaxf(m, p_s[n]);
        float sum = 0.0f;
        for (int n = 0; n < NCLS; ++n) sum += __expf(p_s[n] - m);
        lse_s = m + __logf(sum);
    }
    __syncthreads();
    if (tid < NCLS) {
        const float v = p_s[tid] - lse_s;
        if constexpr (BF) ((bf16*)out)[b * NCLS + tid] = __float2bfloat16(v);
        else              ((float*)out)[b * NCLS + tid] = v;
    }
}

// ---------------------------------------------------------------------------
extern "C" void kernel_launch(void* const* d_in, const int* in_sizes, int n_in,
                              void* d_out, int out_size, void* d_ws, size_t ws_size,
                              hipStream_t stream) {
    const int*  x   = (const int*)d_in[0];
    const void* emb = d_in[1];
    const void* Wfx = d_in[2];
    const void* Wfc = d_in[3];
    const void* bfv = d_in[4];
    const void* Wix = d_in[5];
    const void* Wic = d_in[6];
    const void* biv = d_in[7];
    const void* Wox = d_in[8];
    const void* Woc = d_in[9];
    const void* bov = d_in[10];
    const void* Wcx = d_in[11];
    const void* bcv = d_in[12];
    const void* Wph = d_in[13];
    const void* bp  = d_in[14];

    int*   flag   = (int*)((char*)d_ws + WS_FLAG);
    int*   tstart = (int*)((char*)d_ws + WS_TSTART);
    float* G      = (float*)((char*)d_ws + WS_G);
    float* Ct0    = (float*)((char*)d_ws + WS_CT0);
    float* Ct1    = (float*)((char*)d_ws + WS_CT1);
    float* Hfb    = (float*)((char*)d_ws + WS_HFB);

    detect_mode<<<1, 64, 0, stream>>>((const uint32_t*)emb, flag);
    scan_tstart<<<1, BB, 0, stream>>>(x, tstart);

    build_G<false><<<dim3(NEMB, 8), 256, 0, stream>>>(flag, emb, Wfx, Wix, Wox, Wcx,
                                                      bfv, biv, bov, bcv, G);
    build_G<true ><<<dim3(NEMB, 8), 256, 0, stream>>>(flag, emb, Wfx, Wix, Wox, Wcx,
                                                      bfv, biv, bov, bcv, G);

    {
        void* args[] = {(void*)&flag, (void*)&tstart, (void*)&x, (void*)&G,
                        (void*)&Wfc, (void*)&Wic, (void*)&Woc,
                        (void*)&Ct0, (void*)&Ct1, (void*)&Hfb};
        hipLaunchCooperativeKernel((const void*)recur_cp<false>, dim3(NWG), dim3(512),
                                   args, 0, stream);
        hipLaunchCooperativeKernel((const void*)recur_cp<true>, dim3(NWG), dim3(512),
                                   args, 0, stream);
    }

    proj<false><<<BB, 128, 0, stream>>>(flag, Hfb, Wph, bp, d_out);
    proj<true ><<<BB, 128, 0, stream>>>(flag, Hfb, Wph, bp, d_out);
}

// Round 5
// 10249.298 us; speedup vs baseline: 2.3381x; 1.6353x over previous
//
#include <hip/hip_runtime.h>
#include <hip/hip_bf16.h>
#include <stdint.h>

#define HD   512   // hidden dim H
#define ID   128   // input dim I
#define NCLS 100   // num classes
#define TT   512   // sequence length T
#define BB   128   // batch B
#define NEMB 101   // NC + 1 embedding rows
#define NGRP 32    // independent batch groups
#define GWG  8     // workgroups per group (sync clique)
#define RPG  4     // batch rows per group
#define COLS 64    // hidden cols per WG (GWG*COLS == HD)

// workspace layout (bytes)
#define WS_FLAG 0
#define WS_BAR  1024                  // uint bars[NGRP*32] (128 B apart)
#define WS_G    16384                 // float G[101][2048]  (808 KB)
#define WS_C0   (1u * 1024 * 1024)    // float C0[128][512]  (256 KB)
#define WS_C1   (WS_C0 + 262144)      // float C1[128][512]  (256 KB)
#define WS_HFB  (WS_C1 + 262144)      // float Hfb[128][512] (256 KB)

using bf16 = __hip_bfloat16;

__device__ __forceinline__ float b2f(bf16 v) { return __bfloat162float(v); }
__device__ __forceinline__ float sigf(float x) { return 1.0f / (1.0f + __expf(-x)); }

template <bool BF>
__device__ __forceinline__ float ldv(const void* p, int i) {
    if constexpr (BF) return b2f(((const bf16*)p)[i]);
    else              return ((const float*)p)[i];
}

// ---------------------------------------------------------------------------
// Dtype sniffer + barrier zeroing. emb row 0 is exactly 0.0 by construction:
// bytes [256,512) are zero iff f32 (row 0) and nonzero iff bf16 (row 1).
// ---------------------------------------------------------------------------
__global__ void init_k(const uint32_t* __restrict__ emb_raw,
                       int* __restrict__ flag, unsigned int* __restrict__ bars) {
    const int t = threadIdx.x;
    if (t < NGRP * 32) bars[t] = 0u;
    if (t == 0) {
        uint32_t acc = 0;
        for (int i = 64; i < 128; ++i) acc |= emb_raw[i];
        *flag = (acc == 0u) ? 0 : 1;
    }
}

// ---------------------------------------------------------------------------
// G[c][j]: input-side gate pre-activations per class. j = q*512 + col,
// q in {0:f, 1:i, 2:o, 3:ctilde}; ctilde quarter pre-sigmoided.
// ---------------------------------------------------------------------------
template <bool BF>
__global__ void build_G(const int* __restrict__ flag,
                        const void* __restrict__ emb,
                        const void* __restrict__ Wfx, const void* __restrict__ Wix,
                        const void* __restrict__ Wox, const void* __restrict__ Wcx,
                        const void* __restrict__ bfv, const void* __restrict__ biv,
                        const void* __restrict__ bov, const void* __restrict__ bcv,
                        float* __restrict__ G) {
    if (*flag != (BF ? 1 : 0)) return;
    const int c   = blockIdx.x;
    const int j   = blockIdx.y * 256 + threadIdx.x;
    const int q   = j >> 9;
    const int col = j & 511;
    const void* W  = (q == 0) ? Wfx : (q == 1) ? Wix : (q == 2) ? Wox : Wcx;
    const void* bv = (q == 0) ? bfv : (q == 1) ? biv : (q == 2) ? bov : bcv;
    float acc = ldv<BF>(bv, col);
    for (int i = 0; i < ID; ++i)
        acc += ldv<BF>(emb, c * ID + i) * ldv<BF>(W, i * HD + col);
    if (q == 3) acc = sigf(acc);
    G[c * 2048 + j] = acc;
}

// ---------------------------------------------------------------------------
// Group-local barrier: 8 WGs, monotonic counter, device-scope fences.
// __syncthreads drains each thread's stores (vmcnt(0)) before thread 0's
// release fence; acquire fence before re-reading peers' C slices.
// ---------------------------------------------------------------------------
__device__ __forceinline__ void gbarrier(unsigned int* cnt, unsigned int* iter) {
    __syncthreads();
    if (threadIdx.x == 0) {
        __threadfence();
        __hip_atomic_fetch_add(cnt, 1u, __ATOMIC_RELAXED, __HIP_MEMORY_SCOPE_AGENT);
        const unsigned int tgt = (*iter + 1u) * GWG;
        while (__hip_atomic_load(cnt, __ATOMIC_RELAXED, __HIP_MEMORY_SCOPE_AGENT) < tgt)
            __builtin_amdgcn_s_sleep(1);
        __threadfence();
    }
    ++*iter;
    __syncthreads();
}

// ---------------------------------------------------------------------------
// Batch-split recurrence. Group g (8 WGs, XCD-colocated by swizzle) owns rows
// 4g..4g+3. WG rank owns cols h0=64*rank..h0+63; each lane permanently holds
// its f/i weight segment in 128 VGPRs (wave w covers h' in [64w,64w+64)).
// Per step: wave-uniform float4 C loads (global, L2) -> 512 FMA/lane ->
// LDS partial reduce -> 256 update threads apply gates (own C elem in reg)
// -> write 64-col slice -> group barrier. o-gate once at the end.
// ---------------------------------------------------------------------------
template <bool BF>
__global__ __launch_bounds__(512, 2) void recur_bs(
    const int* __restrict__ flag, const int* __restrict__ x,
    const float* __restrict__ G,
    const void* __restrict__ Wfc, const void* __restrict__ Wic,
    const void* __restrict__ Woc,
    float* __restrict__ C0, float* __restrict__ C1,
    float* __restrict__ Hfb, unsigned int* __restrict__ bars)
{
    if (*flag != (BF ? 1 : 0)) return;

    const int blk  = blockIdx.x;
    const int xcd  = blk & 7;            // round-robin heuristic; correctness-free
    const int j    = blk >> 3;
    const int grp  = xcd * 4 + (j >> 3); // 0..31
    const int rank = j & 7;              // 0..7
    const int r0   = grp * RPG;
    const int h0   = rank * COLS;
    const int tid  = threadIdx.x;
    const int w    = tid >> 6;           // wave id = h' segment
    const int l    = tid & 63;           // lane = col within WG
    unsigned int* bar = bars + grp * 32; // 128 B apart

    __shared__ float part[8][64][9];     // padded: stride 9 breaks bank conflicts
    __shared__ float dots[2 * COLS][RPG];
    __shared__ int   idx_s[RPG][TT];
    __shared__ int   lz[RPG];

    // ---- stage x rows, find group start step ----
    for (int r = 0; r < RPG; ++r)
        idx_s[r][tid] = x[(r0 + r) * TT + tid];
    if (tid < RPG) lz[tid] = -1;
    __syncthreads();
    for (int r = 0; r < RPG; ++r)
        if (idx_s[r][tid] == 0) atomicMax(&lz[r], tid);
    __syncthreads();
    const int t0 = min(min(lz[0], lz[1]), min(lz[2], lz[3])) + 1;

    // ---- persistent register weights: wf/wi[k] = W[h'=64w+k][h0+l] ----
    float wf[64], wi[64];
    #pragma unroll
    for (int k = 0; k < 64; ++k) {
        const int hp = w * 64 + k;
        wf[k] = ldv<BF>(Wfc, hp * HD + h0 + l);
        wi[k] = ldv<BF>(Wic, hp * HD + h0 + l);
    }

    // ---- zero our C slices in both buffers ----
    if (tid < COLS * RPG) {
        const int c = tid & 63, r = tid >> 6;
        C0[(r0 + r) * HD + h0 + c] = 0.0f;
        C1[(r0 + r) * HD + h0 + c] = 0.0f;
    }
    unsigned int bi = 0;
    gbarrier(bar, &bi);                  // zeros visible group-wide

    float Creg = 0.0f;                   // update threads' own C element

    for (int t = t0; t < TT; ++t) {
        const float4* cur4 = reinterpret_cast<const float4*>((t & 1) ? C1 : C0);
        float*        nxt  = (t & 1) ? C0 : C1;

        float af0 = 0.f, af1 = 0.f, af2 = 0.f, af3 = 0.f;
        float ai0 = 0.f, ai1 = 0.f, ai2 = 0.f, ai3 = 0.f;
        const int cbase = r0 * 128 + w * 16;
        #pragma unroll
        for (int k2 = 0; k2 < 16; ++k2) {
            const float4 c0v = cur4[cbase + k2];
            const float4 c1v = cur4[cbase + 128 + k2];
            const float4 c2v = cur4[cbase + 256 + k2];
            const float4 c3v = cur4[cbase + 384 + k2];
            const float w0 = wf[4 * k2], w1 = wf[4 * k2 + 1], w2 = wf[4 * k2 + 2], w3 = wf[4 * k2 + 3];
            const float v0 = wi[4 * k2], v1 = wi[4 * k2 + 1], v2 = wi[4 * k2 + 2], v3 = wi[4 * k2 + 3];
            af0 += w0 * c0v.x + w1 * c0v.y + w2 * c0v.z + w3 * c0v.w;
            af1 += w0 * c1v.x + w1 * c1v.y + w2 * c1v.z + w3 * c1v.w;
            af2 += w0 * c2v.x + w1 * c2v.y + w2 * c2v.z + w3 * c2v.w;
            af3 += w0 * c3v.x + w1 * c3v.y + w2 * c3v.z + w3 * c3v.w;
            ai0 += v0 * c0v.x + v1 * c0v.y + v2 * c0v.z + v3 * c0v.w;
            ai1 += v0 * c1v.x + v1 * c1v.y + v2 * c1v.z + v3 * c1v.w;
            ai2 += v0 * c2v.x + v1 * c2v.y + v2 * c2v.z + v3 * c2v.w;
            ai3 += v0 * c3v.x + v1 * c3v.y + v2 * c3v.z + v3 * c3v.w;
        }
        part[w][l][0] = af0; part[w][l][1] = af1; part[w][l][2] = af2; part[w][l][3] = af3;
        part[w][l][4] = ai0; part[w][l][5] = ai1; part[w][l][6] = ai2; part[w][l][7] = ai3;
        __syncthreads();

        // reduce 8 h'-segments: thread t owns (cg = t&127, r = t>>7)
        {
            const int cg = tid & 127, rr = tid >> 7;
            const int sl = cg & 63, slot = (cg >> 6) * 4 + rr;
            float s = 0.0f;
            #pragma unroll
            for (int ww = 0; ww < 8; ++ww) s += part[ww][sl][slot];
            dots[cg][rr] = s;
        }
        __syncthreads();

        // update: thread t<256 owns (col c = t&63, row r = t>>6)
        if (tid < COLS * RPG) {
            const int c = tid & 63, r = tid >> 6;
            const int cl = idx_s[r][t];
            const float df = dots[c][r], di = dots[COLS + c][r];
            const float* Gr = G + cl * 2048;
            const float gf  = Gr[h0 + c];
            const float gi  = Gr[512 + h0 + c];
            const float sgc = Gr[1536 + h0 + c];
            float Cn = sgc * sigf(gi + di) + Creg * sigf(gf + df);
            Cn = (cl > 0) ? Cn : 0.0f;
            Creg = Cn;
            nxt[(r0 + r) * HD + h0 + c] = Cn;
        }
        gbarrier(bar, &bi);
    }

    // ---- o-gate + h, once (h is dead state mid-sequence; TT even -> C0) ----
    const float* fin = C0;
    {
        float ao0 = 0.f, ao1 = 0.f, ao2 = 0.f, ao3 = 0.f;
        #pragma unroll 8
        for (int k = 0; k < 64; ++k) {
            const int hp = w * 64 + k;
            const float wo = ldv<BF>(Woc, hp * HD + h0 + l);
            ao0 += wo * fin[(r0 + 0) * HD + hp];
            ao1 += wo * fin[(r0 + 1) * HD + hp];
            ao2 += wo * fin[(r0 + 2) * HD + hp];
            ao3 += wo * fin[(r0 + 3) * HD + hp];
        }
        part[w][l][0] = ao0; part[w][l][1] = ao1; part[w][l][2] = ao2; part[w][l][3] = ao3;
        __syncthreads();
        if (tid < COLS * RPG) {
            const int c = tid & 63, r = tid >> 6;
            float s = 0.0f;
            #pragma unroll
            for (int ww = 0; ww < 8; ++ww) s += part[ww][c][r];
            const int cl = idx_s[r][TT - 1];
            const float o = sigf(G[cl * 2048 + 1024 + h0 + c] + s);
            Hfb[(r0 + r) * HD + h0 + c] = tanhf(Creg) * o;
        }
    }
}

// ---------------------------------------------------------------------------
// Projection + log_softmax, one WG per batch row.
// ---------------------------------------------------------------------------
template <bool BF>
__global__ __launch_bounds__(128) void proj(
    const int* __restrict__ flag, const float* __restrict__ Hfb,
    const void* __restrict__ Wph, const void* __restrict__ bp,
    void* __restrict__ out)
{
    if (*flag != (BF ? 1 : 0)) return;
    __shared__ __align__(16) float hv[HD];
    __shared__ float p_s[NCLS];
    __shared__ float lse_s;
    const int b   = blockIdx.x;
    const int tid = threadIdx.x;

    reinterpret_cast<float4*>(hv)[tid] =
        reinterpret_cast<const float4*>(Hfb + b * HD)[tid];
    __syncthreads();

    if (tid < NCLS) {
        float p = ldv<BF>(bp, tid);
        for (int h = 0; h < HD; ++h)
            p += hv[h] * ldv<BF>(Wph, h * NCLS + tid);
        p_s[tid] = p;
    }
    __syncthreads();
    if (tid == 0) {
        float m = -1e30f;
        for (int n = 0; n < NCLS; ++n) m = fmaxf(m, p_s[n]);
        float sum = 0.0f;
        for (int n = 0; n < NCLS; ++n) sum += __expf(p_s[n] - m);
        lse_s = m + __logf(sum);
    }
    __syncthreads();
    if (tid < NCLS) {
        const float v = p_s[tid] - lse_s;
        if constexpr (BF) ((bf16*)out)[b * NCLS + tid] = __float2bfloat16(v);
        else              ((float*)out)[b * NCLS + tid] = v;
    }
}

// ---------------------------------------------------------------------------
extern "C" void kernel_launch(void* const* d_in, const int* in_sizes, int n_in,
                              void* d_out, int out_size, void* d_ws, size_t ws_size,
                              hipStream_t stream) {
    const int*  x   = (const int*)d_in[0];
    const void* emb = d_in[1];
    const void* Wfx = d_in[2];
    const void* Wfc = d_in[3];
    const void* bfv = d_in[4];
    const void* Wix = d_in[5];
    const void* Wic = d_in[6];
    const void* biv = d_in[7];
    const void* Wox = d_in[8];
    const void* Woc = d_in[9];
    const void* bov = d_in[10];
    const void* Wcx = d_in[11];
    const void* bcv = d_in[12];
    const void* Wph = d_in[13];
    const void* bp  = d_in[14];

    int*          flag = (int*)((char*)d_ws + WS_FLAG);
    unsigned int* bars = (unsigned int*)((char*)d_ws + WS_BAR);
    float*        G    = (float*)((char*)d_ws + WS_G);
    float*        C0   = (float*)((char*)d_ws + WS_C0);
    float*        C1   = (float*)((char*)d_ws + WS_C1);
    float*        Hfb  = (float*)((char*)d_ws + WS_HFB);

    init_k<<<1, 1024, 0, stream>>>((const uint32_t*)emb, flag, bars);

    build_G<false><<<dim3(NEMB, 8), 256, 0, stream>>>(flag, emb, Wfx, Wix, Wox, Wcx,
                                                      bfv, biv, bov, bcv, G);
    build_G<true ><<<dim3(NEMB, 8), 256, 0, stream>>>(flag, emb, Wfx, Wix, Wox, Wcx,
                                                      bfv, biv, bov, bcv, G);

    {
        void* args[] = {(void*)&flag, (void*)&x, (void*)&G,
                        (void*)&Wfc, (void*)&Wic, (void*)&Woc,
                        (void*)&C0, (void*)&C1, (void*)&Hfb, (void*)&bars};
        hipLaunchCooperativeKernel((const void*)recur_bs<false>, dim3(NGRP * GWG), dim3(512),
                                   args, 0, stream);
        hipLaunchCooperativeKernel((const void*)recur_bs<true>, dim3(NGRP * GWG), dim3(512),
                                   args, 0, stream);
    }

    proj<false><<<BB, 128, 0, stream>>>(flag, Hfb, Wph, bp, d_out);
    proj<true ><<<BB, 128, 0, stream>>>(flag, Hfb, Wph, bp, d_out);
}

// Round 6
// 5370.350 us; speedup vs baseline: 4.4622x; 1.9085x over previous
//
#include <hip/hip_runtime.h>
#include <hip/hip_bf16.h>
#include <stdint.h>

#define HD   512   // hidden dim H
#define ID   128   // input dim I
#define NCLS 100   // num classes
#define TT   512   // sequence length T
#define BB   128   // batch B
#define NEMB 101   // NC + 1 embedding rows
#define NGRP 32    // independent batch groups
#define GWG  8     // workgroups per group (sync clique)
#define RPG  4     // batch rows per group
#define COLS 64    // hidden cols per WG (GWG*COLS == HD)

// workspace layout (bytes)
#define WS_FLAG 0
#define WS_BAR  1024                  // uint bars[NGRP*32] (128 B apart)
#define WS_G    16384                 // float G[101][2048]  (808 KB)
#define WS_C0   (1u * 1024 * 1024)    // float C0[128][512]  (256 KB)
#define WS_C1   (WS_C0 + 262144)      // float C1[128][512]  (256 KB)
#define WS_HFB  (WS_C1 + 262144)      // float Hfb[128][512] (256 KB)

using bf16 = __hip_bfloat16;

__device__ __forceinline__ float b2f(bf16 v) { return __bfloat162float(v); }
__device__ __forceinline__ float sigf(float x) { return 1.0f / (1.0f + expf(-x)); }

// coherent (IF-scope) C-state accessors: sc1 loads/stores bypass the
// non-coherent per-XCD L2 — no fences / cache-maintenance needed.
__device__ __forceinline__ float cld(const float* p) {
    return __hip_atomic_load(p, __ATOMIC_RELAXED, __HIP_MEMORY_SCOPE_AGENT);
}
__device__ __forceinline__ void cst(float* p, float v) {
    __hip_atomic_store(p, v, __ATOMIC_RELAXED, __HIP_MEMORY_SCOPE_AGENT);
}

template <bool BF>
__device__ __forceinline__ float ldv(const void* p, int i) {
    if constexpr (BF) return b2f(((const bf16*)p)[i]);
    else              return ((const float*)p)[i];
}

// ---------------------------------------------------------------------------
// Dtype sniffer + barrier zeroing. emb row 0 is exactly 0.0 by construction:
// bytes [256,512) are zero iff f32 (row 0) and nonzero iff bf16 (row 1).
// ---------------------------------------------------------------------------
__global__ void init_k(const uint32_t* __restrict__ emb_raw,
                       int* __restrict__ flag, unsigned int* __restrict__ bars) {
    const int t = threadIdx.x;
    if (t < NGRP * 32) bars[t] = 0u;
    if (t == 0) {
        uint32_t acc = 0;
        for (int i = 64; i < 128; ++i) acc |= emb_raw[i];
        *flag = (acc == 0u) ? 0 : 1;
    }
}

// ---------------------------------------------------------------------------
// G[c][j]: input-side gate pre-activations per class. j = q*512 + col,
// q in {0:f, 1:i, 2:o, 3:ctilde}; ctilde quarter pre-sigmoided.
// ---------------------------------------------------------------------------
template <bool BF>
__global__ void build_G(const int* __restrict__ flag,
                        const void* __restrict__ emb,
                        const void* __restrict__ Wfx, const void* __restrict__ Wix,
                        const void* __restrict__ Wox, const void* __restrict__ Wcx,
                        const void* __restrict__ bfv, const void* __restrict__ biv,
                        const void* __restrict__ bov, const void* __restrict__ bcv,
                        float* __restrict__ G) {
    if (*flag != (BF ? 1 : 0)) return;
    const int c   = blockIdx.x;
    const int j   = blockIdx.y * 256 + threadIdx.x;
    const int q   = j >> 9;
    const int col = j & 511;
    const void* W  = (q == 0) ? Wfx : (q == 1) ? Wix : (q == 2) ? Wox : Wcx;
    const void* bv = (q == 0) ? bfv : (q == 1) ? biv : (q == 2) ? bov : bcv;
    float acc = ldv<BF>(bv, col);
    for (int i = 0; i < ID; ++i)
        acc += ldv<BF>(emb, c * ID + i) * ldv<BF>(W, i * HD + col);
    if (q == 3) acc = sigf(acc);
    G[c * 2048 + j] = acc;
}

// ---------------------------------------------------------------------------
// Group-local barrier, FENCE-FREE. __syncthreads drains each wave's sc1 C
// stores (compiler emits s_waitcnt vmcnt(0) before s_barrier), so by the time
// the leader's relaxed agent atomicAdd lands at the IF, this WG's C slice is
// IF-visible. Readers use sc1 loads, so no invalidate is needed either.
// ---------------------------------------------------------------------------
__device__ __forceinline__ void gbarrier(unsigned int* cnt, unsigned int* iter) {
    __syncthreads();
    if (threadIdx.x == 0) {
        __hip_atomic_fetch_add(cnt, 1u, __ATOMIC_RELAXED, __HIP_MEMORY_SCOPE_AGENT);
        const unsigned int tgt = (*iter + 1u) * GWG;
        while (__hip_atomic_load(cnt, __ATOMIC_RELAXED, __HIP_MEMORY_SCOPE_AGENT) < tgt)
            __builtin_amdgcn_s_sleep(2);
    }
    ++*iter;
    __syncthreads();
}

// ---------------------------------------------------------------------------
// Batch-split recurrence. Group g (8 WGs) owns rows 4g..4g+3. WG rank owns
// cols h0=64*rank..h0+63; each lane permanently holds its f/i weight segment
// in 128 VGPRs (wave w covers h' in [64w,64w+64)). Per step: wave-uniform
// sc1 C loads -> 512 FMA/lane -> LDS partial reduce -> 256 update threads
// apply gates (own C elem in reg) -> sc1-write 64-col slice -> group barrier.
// o-gate once at the end (h is dead state mid-sequence).
// ---------------------------------------------------------------------------
template <bool BF>
__global__ __launch_bounds__(512, 2) void recur_bs(
    const int* __restrict__ flag, const int* __restrict__ x,
    const float* __restrict__ G,
    const void* __restrict__ Wfc, const void* __restrict__ Wic,
    const void* __restrict__ Woc,
    float* __restrict__ C0, float* __restrict__ C1,
    float* __restrict__ Hfb, unsigned int* __restrict__ bars)
{
    if (*flag != (BF ? 1 : 0)) return;

    const int blk  = blockIdx.x;
    const int grp  = (blk & 7) * 4 + ((blk >> 3) >> 3);  // 0..31
    const int rank = (blk >> 3) & 7;                     // 0..7
    const int r0   = grp * RPG;
    const int h0   = rank * COLS;
    const int tid  = threadIdx.x;
    const int w    = tid >> 6;           // wave id = h' segment
    const int l    = tid & 63;           // lane = col within WG
    unsigned int* bar = bars + grp * 32; // 128 B apart

    __shared__ float part[8][64][9];     // padded: stride 9 breaks bank conflicts
    __shared__ float dots[2 * COLS][RPG];
    __shared__ int   idx_s[RPG][TT];
    __shared__ int   lz[RPG];

    // ---- stage x rows, find group start step ----
    for (int r = 0; r < RPG; ++r)
        idx_s[r][tid] = x[(r0 + r) * TT + tid];
    if (tid < RPG) lz[tid] = -1;
    __syncthreads();
    for (int r = 0; r < RPG; ++r)
        if (idx_s[r][tid] == 0) atomicMax(&lz[r], tid);
    __syncthreads();
    const int t0 = min(min(lz[0], lz[1]), min(lz[2], lz[3])) + 1;

    // ---- persistent register weights: wf/wi[k] = W[h'=64w+k][h0+l] ----
    float wf[64], wi[64];
    #pragma unroll
    for (int k = 0; k < 64; ++k) {
        const int hp = w * 64 + k;
        wf[k] = ldv<BF>(Wfc, hp * HD + h0 + l);
        wi[k] = ldv<BF>(Wic, hp * HD + h0 + l);
    }

    // ---- zero our C slices in both buffers (coherent stores) ----
    if (tid < COLS * RPG) {
        const int c = tid & 63, r = tid >> 6;
        cst(&C0[(r0 + r) * HD + h0 + c], 0.0f);
        cst(&C1[(r0 + r) * HD + h0 + c], 0.0f);
    }
    unsigned int bi = 0;
    gbarrier(bar, &bi);                  // zeros visible group-wide

    float Creg = 0.0f;                   // update threads' own C element

    for (int t = t0; t < TT; ++t) {
        const float* cur = (t & 1) ? C1 : C0;
        float*       nxt = (t & 1) ? C0 : C1;

        float af0 = 0.f, af1 = 0.f, af2 = 0.f, af3 = 0.f;
        float ai0 = 0.f, ai1 = 0.f, ai2 = 0.f, ai3 = 0.f;
        const float* cb = cur + r0 * HD + w * 64;
        #pragma unroll 8
        for (int k = 0; k < 64; ++k) {
            const float c0v = cld(cb + k);
            const float c1v = cld(cb + HD + k);
            const float c2v = cld(cb + 2 * HD + k);
            const float c3v = cld(cb + 3 * HD + k);
            const float wfk = wf[k], wik = wi[k];
            af0 += wfk * c0v; af1 += wfk * c1v; af2 += wfk * c2v; af3 += wfk * c3v;
            ai0 += wik * c0v; ai1 += wik * c1v; ai2 += wik * c2v; ai3 += wik * c3v;
        }
        part[w][l][0] = af0; part[w][l][1] = af1; part[w][l][2] = af2; part[w][l][3] = af3;
        part[w][l][4] = ai0; part[w][l][5] = ai1; part[w][l][6] = ai2; part[w][l][7] = ai3;
        __syncthreads();

        // reduce 8 h'-segments: thread t owns (cg = t&127, r = t>>7)
        {
            const int cg = tid & 127, rr = tid >> 7;
            const int sl = cg & 63, slot = (cg >> 6) * 4 + rr;
            float s = 0.0f;
            #pragma unroll
            for (int ww = 0; ww < 8; ++ww) s += part[ww][sl][slot];
            dots[cg][rr] = s;
        }
        __syncthreads();

        // update: thread t<256 owns (col c = t&63, row r = t>>6)
        if (tid < COLS * RPG) {
            const int c = tid & 63, r = tid >> 6;
            const int cl = idx_s[r][t];
            const float df = dots[c][r], di = dots[COLS + c][r];
            const float* Gr = G + cl * 2048;
            const float gf  = Gr[h0 + c];
            const float gi  = Gr[512 + h0 + c];
            const float sgc = Gr[1536 + h0 + c];
            float Cn = sgc * sigf(gi + di) + Creg * sigf(gf + df);
            Cn = (cl > 0) ? Cn : 0.0f;
            Creg = Cn;
            cst(&nxt[(r0 + r) * HD + h0 + c], Cn);
        }
        gbarrier(bar, &bi);
    }

    // ---- o-gate + h, once (TT even -> final C in C0) ----
    const float* fin = C0;
    {
        float ao0 = 0.f, ao1 = 0.f, ao2 = 0.f, ao3 = 0.f;
        const float* cb = fin + r0 * HD + w * 64;
        #pragma unroll 8
        for (int k = 0; k < 64; ++k) {
            const int hp = w * 64 + k;
            const float wo = ldv<BF>(Woc, hp * HD + h0 + l);
            ao0 += wo * cld(cb + k);
            ao1 += wo * cld(cb + HD + k);
            ao2 += wo * cld(cb + 2 * HD + k);
            ao3 += wo * cld(cb + 3 * HD + k);
        }
        part[w][l][0] = ao0; part[w][l][1] = ao1; part[w][l][2] = ao2; part[w][l][3] = ao3;
        __syncthreads();
        if (tid < COLS * RPG) {
            const int c = tid & 63, r = tid >> 6;
            float s = 0.0f;
            #pragma unroll
            for (int ww = 0; ww < 8; ++ww) s += part[ww][c][r];
            const int cl = idx_s[r][TT - 1];
            const float o = sigf(G[cl * 2048 + 1024 + h0 + c] + s);
            Hfb[(r0 + r) * HD + h0 + c] = tanhf(Creg) * o;
        }
    }
}

// ---------------------------------------------------------------------------
// Projection + log_softmax, one WG per batch row.
// ---------------------------------------------------------------------------
template <bool BF>
__global__ __launch_bounds__(128) void proj(
    const int* __restrict__ flag, const float* __restrict__ Hfb,
    const void* __restrict__ Wph, const void* __restrict__ bp,
    void* __restrict__ out)
{
    if (*flag != (BF ? 1 : 0)) return;
    __shared__ __align__(16) float hv[HD];
    __shared__ float p_s[NCLS];
    __shared__ float lse_s;
    const int b   = blockIdx.x;
    const int tid = threadIdx.x;

    reinterpret_cast<float4*>(hv)[tid] =
        reinterpret_cast<const float4*>(Hfb + b * HD)[tid];
    __syncthreads();

    if (tid < NCLS) {
        float p = ldv<BF>(bp, tid);
        for (int h = 0; h < HD; ++h)
            p += hv[h] * ldv<BF>(Wph, h * NCLS + tid);
        p_s[tid] = p;
    }
    __syncthreads();
    if (tid == 0) {
        float m = -1e30f;
        for (int n = 0; n < NCLS; ++n) m = fmaxf(m, p_s[n]);
        float sum = 0.0f;
        for (int n = 0; n < NCLS; ++n) sum += expf(p_s[n] - m);
        lse_s = m + logf(sum);
    }
    __syncthreads();
    if (tid < NCLS) {
        const float v = p_s[tid] - lse_s;
        if constexpr (BF) ((bf16*)out)[b * NCLS + tid] = __float2bfloat16(v);
        else              ((float*)out)[b * NCLS + tid] = v;
    }
}

// ---------------------------------------------------------------------------
extern "C" void kernel_launch(void* const* d_in, const int* in_sizes, int n_in,
                              void* d_out, int out_size, void* d_ws, size_t ws_size,
                              hipStream_t stream) {
    const int*  x   = (const int*)d_in[0];
    const void* emb = d_in[1];
    const void* Wfx = d_in[2];
    const void* Wfc = d_in[3];
    const void* bfv = d_in[4];
    const void* Wix = d_in[5];
    const void* Wic = d_in[6];
    const void* biv = d_in[7];
    const void* Wox = d_in[8];
    const void* Woc = d_in[9];
    const void* bov = d_in[10];
    const void* Wcx = d_in[11];
    const void* bcv = d_in[12];
    const void* Wph = d_in[13];
    const void* bp  = d_in[14];

    int*          flag = (int*)((char*)d_ws + WS_FLAG);
    unsigned int* bars = (unsigned int*)((char*)d_ws + WS_BAR);
    float*        G    = (float*)((char*)d_ws + WS_G);
    float*        C0   = (float*)((char*)d_ws + WS_C0);
    float*        C1   = (float*)((char*)d_ws + WS_C1);
    float*        Hfb  = (float*)((char*)d_ws + WS_HFB);

    init_k<<<1, 1024, 0, stream>>>((const uint32_t*)emb, flag, bars);

    build_G<false><<<dim3(NEMB, 8), 256, 0, stream>>>(flag, emb, Wfx, Wix, Wox, Wcx,
                                                      bfv, biv, bov, bcv, G);
    build_G<true ><<<dim3(NEMB, 8), 256, 0, stream>>>(flag, emb, Wfx, Wix, Wox, Wcx,
                                                      bfv, biv, bov, bcv, G);

    {
        void* args[] = {(void*)&flag, (void*)&x, (void*)&G,
                        (void*)&Wfc, (void*)&Wic, (void*)&Woc,
                        (void*)&C0, (void*)&C1, (void*)&Hfb, (void*)&bars};
        hipLaunchCooperativeKernel((const void*)recur_bs<false>, dim3(NGRP * GWG), dim3(512),
                                   args, 0, stream);
        hipLaunchCooperativeKernel((const void*)recur_bs<true>, dim3(NGRP * GWG), dim3(512),
                                   args, 0, stream);
    }

    proj<false><<<BB, 128, 0, stream>>>(flag, Hfb, Wph, bp, d_out);
    proj<true ><<<BB, 128, 0, stream>>>(flag, Hfb, Wph, bp, d_out);
}

// Round 7
// 4745.848 us; speedup vs baseline: 5.0494x; 1.1316x over previous
//
#include <hip/hip_runtime.h>
#include <hip/hip_bf16.h>
#include <stdint.h>

#define HD   512   // hidden dim H
#define ID   128   // input dim I
#define NCLS 100   // num classes
#define TT   512   // sequence length T
#define BB   128   // batch B
#define NEMB 101   // NC + 1 embedding rows
#define NGRP 32    // independent batch groups
#define GWG  8     // workgroups per group (sync clique)
#define RPG  4     // batch rows per group
#define COLS 64    // hidden cols per WG (GWG*COLS == HD)
#define CPAD 520   // LDS C row stride (8-float pad: keeps 16B align, skews banks)

// workspace layout (bytes)
#define WS_FLAG 0
#define WS_BAR  1024                  // uint bars[NGRP*32] (128 B apart)
#define WS_G    16384                 // float G[101][2048]  (808 KB)
#define WS_C0   (1u * 1024 * 1024)    // float C0[128][512]  (256 KB)
#define WS_C1   (WS_C0 + 262144)      // float C1[128][512]  (256 KB)
#define WS_HFB  (WS_C1 + 262144)      // float Hfb[128][512] (256 KB)

using bf16 = __hip_bfloat16;

__device__ __forceinline__ float b2f(bf16 v) { return __bfloat162float(v); }
__device__ __forceinline__ float sigf(float x) { return 1.0f / (1.0f + expf(-x)); }

// coherent (IF-scope) C-state accessors: sc1 loads/stores bypass the
// non-coherent per-XCD L2 — no fences / cache-maintenance needed.
__device__ __forceinline__ float cld(const float* p) {
    return __hip_atomic_load(p, __ATOMIC_RELAXED, __HIP_MEMORY_SCOPE_AGENT);
}
__device__ __forceinline__ void cst(float* p, float v) {
    __hip_atomic_store(p, v, __ATOMIC_RELAXED, __HIP_MEMORY_SCOPE_AGENT);
}

template <bool BF>
__device__ __forceinline__ float ldv(const void* p, int i) {
    if constexpr (BF) return b2f(((const bf16*)p)[i]);
    else              return ((const float*)p)[i];
}

// ---------------------------------------------------------------------------
// Dtype sniffer + barrier zeroing. emb row 0 is exactly 0.0 by construction:
// bytes [256,512) are zero iff f32 (row 0) and nonzero iff bf16 (row 1).
// ---------------------------------------------------------------------------
__global__ void init_k(const uint32_t* __restrict__ emb_raw,
                       int* __restrict__ flag, unsigned int* __restrict__ bars) {
    const int t = threadIdx.x;
    if (t < NGRP * 32) bars[t] = 0u;
    if (t == 0) {
        uint32_t acc = 0;
        for (int i = 64; i < 128; ++i) acc |= emb_raw[i];
        *flag = (acc == 0u) ? 0 : 1;
    }
}

// ---------------------------------------------------------------------------
// G[c][j]: input-side gate pre-activations per class. j = q*512 + col,
// q in {0:f, 1:i, 2:o, 3:ctilde}; ctilde quarter pre-sigmoided.
// ---------------------------------------------------------------------------
template <bool BF>
__global__ void build_G(const int* __restrict__ flag,
                        const void* __restrict__ emb,
                        const void* __restrict__ Wfx, const void* __restrict__ Wix,
                        const void* __restrict__ Wox, const void* __restrict__ Wcx,
                        const void* __restrict__ bfv, const void* __restrict__ biv,
                        const void* __restrict__ bov, const void* __restrict__ bcv,
                        float* __restrict__ G) {
    if (*flag != (BF ? 1 : 0)) return;
    const int c   = blockIdx.x;
    const int j   = blockIdx.y * 256 + threadIdx.x;
    const int q   = j >> 9;
    const int col = j & 511;
    const void* W  = (q == 0) ? Wfx : (q == 1) ? Wix : (q == 2) ? Wox : Wcx;
    const void* bv = (q == 0) ? bfv : (q == 1) ? biv : (q == 2) ? bov : bcv;
    float acc = ldv<BF>(bv, col);
    for (int i = 0; i < ID; ++i)
        acc += ldv<BF>(emb, c * ID + i) * ldv<BF>(W, i * HD + col);
    if (q == 3) acc = sigf(acc);
    G[c * 2048 + j] = acc;
}

// ---------------------------------------------------------------------------
// Group-local barrier, fence-free (sc1 data path + relaxed agent atomics).
// __syncthreads drains each wave's sc1 C stores before the leader's add.
// ---------------------------------------------------------------------------
__device__ __forceinline__ void gbarrier(unsigned int* cnt, unsigned int* iter) {
    __syncthreads();
    if (threadIdx.x == 0) {
        __hip_atomic_fetch_add(cnt, 1u, __ATOMIC_RELAXED, __HIP_MEMORY_SCOPE_AGENT);
        const unsigned int tgt = (*iter + 1u) * GWG;
        while (__hip_atomic_load(cnt, __ATOMIC_RELAXED, __HIP_MEMORY_SCOPE_AGENT) < tgt)
            __builtin_amdgcn_s_sleep(1);
    }
    ++*iter;
    __syncthreads();
}

// ---------------------------------------------------------------------------
// Batch-split recurrence. Group g (8 WGs) owns rows 4g..4g+3; WG rank owns
// cols h0=64*rank..h0+63. Weights (f,i for 64 h' x own col) are pinned in
// VGPRs via inline-asm (128 f32/thread). Per step:
//   stage C(t) into LDS (4 coalesced sc1 loads/thread) -> sync
//   wave w: 64 broadcast ds_read_b128 of its h' segment + 512 pinned-reg FMA
//   LDS partial reduce -> 256 update threads apply gates (own C elem in reg)
//   sc1-write 64-col slice -> group barrier.
// o-gate once at the end (h is dead state mid-sequence).
// ---------------------------------------------------------------------------
template <bool BF>
__global__ __launch_bounds__(512, 2) void recur_bs(
    const int* __restrict__ flag, const int* __restrict__ x,
    const float* __restrict__ G,
    const void* __restrict__ Wfc, const void* __restrict__ Wic,
    const void* __restrict__ Woc,
    float* __restrict__ C0, float* __restrict__ C1,
    float* __restrict__ Hfb, unsigned int* __restrict__ bars)
{
    if (*flag != (BF ? 1 : 0)) return;

    const int blk  = blockIdx.x;
    const int grp  = (blk & 7) * 4 + ((blk >> 3) >> 3);  // 0..31
    const int rank = (blk >> 3) & 7;                     // 0..7
    const int r0   = grp * RPG;
    const int h0   = rank * COLS;
    const int tid  = threadIdx.x;
    const int w    = tid >> 6;           // wave id = h' segment
    const int l    = tid & 63;           // lane = col within WG
    unsigned int* bar = bars + grp * 32; // 128 B apart

    __shared__ __align__(16) float Cs[RPG * CPAD];   // staged C(t), padded rows
    __shared__ float part[8][64][9];     // padded: stride 9 breaks bank conflicts
    __shared__ float dots[2 * COLS][RPG];
    __shared__ int   idx_s[RPG][TT];
    __shared__ int   lz[RPG];

    // ---- stage x rows, find group start step ----
    for (int r = 0; r < RPG; ++r)
        idx_s[r][tid] = x[(r0 + r) * TT + tid];
    if (tid < RPG) lz[tid] = -1;
    __syncthreads();
    for (int r = 0; r < RPG; ++r)
        if (idx_s[r][tid] == 0) atomicMax(&lz[r], tid);
    __syncthreads();
    const int t0 = min(min(lz[0], lz[1]), min(lz[2], lz[3])) + 1;

    // ---- persistent register weights, pinned so they can't rematerialize ----
    float wf[64], wi[64];
    #pragma unroll
    for (int k = 0; k < 64; ++k) {
        const int hp = w * 64 + k;
        wf[k] = ldv<BF>(Wfc, hp * HD + h0 + l);
        wi[k] = ldv<BF>(Wic, hp * HD + h0 + l);
    }
    #pragma unroll
    for (int k = 0; k < 64; ++k)
        asm volatile("" : "+v"(wf[k]), "+v"(wi[k]));

    // ---- zero our C slices in both buffers (coherent stores) ----
    if (tid < COLS * RPG) {
        const int c = tid & 63, r = tid >> 6;
        cst(&C0[(r0 + r) * HD + h0 + c], 0.0f);
        cst(&C1[(r0 + r) * HD + h0 + c], 0.0f);
    }
    unsigned int bi = 0;
    gbarrier(bar, &bi);                  // zeros visible group-wide

    float Creg = 0.0f;                   // update threads' own C element

    for (int t = t0; t < TT; ++t) {
        const float* cur = (t & 1) ? C1 : C0;
        float*       nxt = (t & 1) ? C0 : C1;

        // ---- stage C(t) into LDS: thread tid loads C[row j][h'=tid] ----
        {
            const float* cb = cur + r0 * HD + tid;
            float v0 = cld(cb);
            float v1 = cld(cb + HD);
            float v2 = cld(cb + 2 * HD);
            float v3 = cld(cb + 3 * HD);
            Cs[0 * CPAD + tid] = v0;
            Cs[1 * CPAD + tid] = v1;
            Cs[2 * CPAD + tid] = v2;
            Cs[3 * CPAD + tid] = v3;
        }
        __syncthreads();

        // ---- own-col partial dots over h' in [64w, 64w+64) ----
        float af0 = 0.f, af1 = 0.f, af2 = 0.f, af3 = 0.f;
        float ai0 = 0.f, ai1 = 0.f, ai2 = 0.f, ai3 = 0.f;
        {
            const float4* c4r0 = reinterpret_cast<const float4*>(Cs + 0 * CPAD + w * 64);
            const float4* c4r1 = reinterpret_cast<const float4*>(Cs + 1 * CPAD + w * 64);
            const float4* c4r2 = reinterpret_cast<const float4*>(Cs + 2 * CPAD + w * 64);
            const float4* c4r3 = reinterpret_cast<const float4*>(Cs + 3 * CPAD + w * 64);
            #pragma unroll
            for (int j = 0; j < 16; ++j) {
                const float4 c0v = c4r0[j];
                const float4 c1v = c4r1[j];
                const float4 c2v = c4r2[j];
                const float4 c3v = c4r3[j];
                const float w0 = wf[4 * j], w1 = wf[4 * j + 1], w2 = wf[4 * j + 2], w3 = wf[4 * j + 3];
                const float v0 = wi[4 * j], v1 = wi[4 * j + 1], v2 = wi[4 * j + 2], v3 = wi[4 * j + 3];
                af0 += w0 * c0v.x + w1 * c0v.y + w2 * c0v.z + w3 * c0v.w;
                af1 += w0 * c1v.x + w1 * c1v.y + w2 * c1v.z + w3 * c1v.w;
                af2 += w0 * c2v.x + w1 * c2v.y + w2 * c2v.z + w3 * c2v.w;
                af3 += w0 * c3v.x + w1 * c3v.y + w2 * c3v.z + w3 * c3v.w;
                ai0 += v0 * c0v.x + v1 * c0v.y + v2 * c0v.z + v3 * c0v.w;
                ai1 += v0 * c1v.x + v1 * c1v.y + v2 * c1v.z + v3 * c1v.w;
                ai2 += v0 * c2v.x + v1 * c2v.y + v2 * c2v.z + v3 * c2v.w;
                ai3 += v0 * c3v.x + v1 * c3v.y + v2 * c3v.z + v3 * c3v.w;
            }
        }
        part[w][l][0] = af0; part[w][l][1] = af1; part[w][l][2] = af2; part[w][l][3] = af3;
        part[w][l][4] = ai0; part[w][l][5] = ai1; part[w][l][6] = ai2; part[w][l][7] = ai3;
        __syncthreads();

        // reduce 8 h'-segments: thread t owns (cg = t&127, r = t>>7)
        {
            const int cg = tid & 127, rr = tid >> 7;
            const int sl = cg & 63, slot = (cg >> 6) * 4 + rr;
            float s = 0.0f;
            #pragma unroll
            for (int ww = 0; ww < 8; ++ww) s += part[ww][sl][slot];
            dots[cg][rr] = s;
        }
        __syncthreads();

        // update: thread t<256 owns (col c = t&63, row r = t>>6)
        if (tid < COLS * RPG) {
            const int c = tid & 63, r = tid >> 6;
            const int cl = idx_s[r][t];
            const float df = dots[c][r], di = dots[COLS + c][r];
            const float* Gr = G + cl * 2048;
            const float gf  = Gr[h0 + c];
            const float gi  = Gr[512 + h0 + c];
            const float sgc = Gr[1536 + h0 + c];
            float Cn = sgc * sigf(gi + di) + Creg * sigf(gf + df);
            Cn = (cl > 0) ? Cn : 0.0f;
            Creg = Cn;
            cst(&nxt[(r0 + r) * HD + h0 + c], Cn);
        }
        gbarrier(bar, &bi);
    }

    // ---- o-gate + h, once (TT even -> final C in C0) ----
    {
        const float* fin = C0;
        const float* cb = fin + r0 * HD + tid;
        float v0 = cld(cb);
        float v1 = cld(cb + HD);
        float v2 = cld(cb + 2 * HD);
        float v3 = cld(cb + 3 * HD);
        Cs[0 * CPAD + tid] = v0;
        Cs[1 * CPAD + tid] = v1;
        Cs[2 * CPAD + tid] = v2;
        Cs[3 * CPAD + tid] = v3;
        __syncthreads();

        float ao0 = 0.f, ao1 = 0.f, ao2 = 0.f, ao3 = 0.f;
        #pragma unroll 8
        for (int k = 0; k < 64; ++k) {
            const int hp = w * 64 + k;
            const float wo = ldv<BF>(Woc, hp * HD + h0 + l);
            ao0 += wo * Cs[0 * CPAD + hp];
            ao1 += wo * Cs[1 * CPAD + hp];
            ao2 += wo * Cs[2 * CPAD + hp];
            ao3 += wo * Cs[3 * CPAD + hp];
        }
        part[w][l][0] = ao0; part[w][l][1] = ao1; part[w][l][2] = ao2; part[w][l][3] = ao3;
        __syncthreads();
        if (tid < COLS * RPG) {
            const int c = tid & 63, r = tid >> 6;
            float s = 0.0f;
            #pragma unroll
            for (int ww = 0; ww < 8; ++ww) s += part[ww][c][r];
            const int cl = idx_s[r][TT - 1];
            const float o = sigf(G[cl * 2048 + 1024 + h0 + c] + s);
            Hfb[(r0 + r) * HD + h0 + c] = tanhf(Creg) * o;
        }
    }
}

// ---------------------------------------------------------------------------
// Projection + log_softmax, one WG per batch row.
// ---------------------------------------------------------------------------
template <bool BF>
__global__ __launch_bounds__(128) void proj(
    const int* __restrict__ flag, const float* __restrict__ Hfb,
    const void* __restrict__ Wph, const void* __restrict__ bp,
    void* __restrict__ out)
{
    if (*flag != (BF ? 1 : 0)) return;
    __shared__ __align__(16) float hv[HD];
    __shared__ float p_s[NCLS];
    __shared__ float lse_s;
    const int b   = blockIdx.x;
    const int tid = threadIdx.x;

    reinterpret_cast<float4*>(hv)[tid] =
        reinterpret_cast<const float4*>(Hfb + b * HD)[tid];
    __syncthreads();

    if (tid < NCLS) {
        float p = ldv<BF>(bp, tid);
        for (int h = 0; h < HD; ++h)
            p += hv[h] * ldv<BF>(Wph, h * NCLS + tid);
        p_s[tid] = p;
    }
    __syncthreads();
    if (tid == 0) {
        float m = -1e30f;
        for (int n = 0; n < NCLS; ++n) m = fmaxf(m, p_s[n]);
        float sum = 0.0f;
        for (int n = 0; n < NCLS; ++n) sum += expf(p_s[n] - m);
        lse_s = m + logf(sum);
    }
    __syncthreads();
    if (tid < NCLS) {
        const float v = p_s[tid] - lse_s;
        if constexpr (BF) ((bf16*)out)[b * NCLS + tid] = __float2bfloat16(v);
        else              ((float*)out)[b * NCLS + tid] = v;
    }
}

// ---------------------------------------------------------------------------
extern "C" void kernel_launch(void* const* d_in, const int* in_sizes, int n_in,
                              void* d_out, int out_size, void* d_ws, size_t ws_size,
                              hipStream_t stream) {
    const int*  x   = (const int*)d_in[0];
    const void* emb = d_in[1];
    const void* Wfx = d_in[2];
    const void* Wfc = d_in[3];
    const void* bfv = d_in[4];
    const void* Wix = d_in[5];
    const void* Wic = d_in[6];
    const void* biv = d_in[7];
    const void* Wox = d_in[8];
    const void* Woc = d_in[9];
    const void* bov = d_in[10];
    const void* Wcx = d_in[11];
    const void* bcv = d_in[12];
    const void* Wph = d_in[13];
    const void* bp  = d_in[14];

    int*          flag = (int*)((char*)d_ws + WS_FLAG);
    unsigned int* bars = (unsigned int*)((char*)d_ws + WS_BAR);
    float*        G    = (float*)((char*)d_ws + WS_G);
    float*        C0   = (float*)((char*)d_ws + WS_C0);
    float*        C1   = (float*)((char*)d_ws + WS_C1);
    float*        Hfb  = (float*)((char*)d_ws + WS_HFB);

    init_k<<<1, 1024, 0, stream>>>((const uint32_t*)emb, flag, bars);

    build_G<false><<<dim3(NEMB, 8), 256, 0, stream>>>(flag, emb, Wfx, Wix, Wox, Wcx,
                                                      bfv, biv, bov, bcv, G);
    build_G<true ><<<dim3(NEMB, 8), 256, 0, stream>>>(flag, emb, Wfx, Wix, Wox, Wcx,
                                                      bfv, biv, bov, bcv, G);

    {
        void* args[] = {(void*)&flag, (void*)&x, (void*)&G,
                        (void*)&Wfc, (void*)&Wic, (void*)&Woc,
                        (void*)&C0, (void*)&C1, (void*)&Hfb, (void*)&bars};
        hipLaunchCooperativeKernel((const void*)recur_bs<false>, dim3(NGRP * GWG), dim3(512),
                                   args, 0, stream);
        hipLaunchCooperativeKernel((const void*)recur_bs<true>, dim3(NGRP * GWG), dim3(512),
                                   args, 0, stream);
    }

    proj<false><<<BB, 128, 0, stream>>>(flag, Hfb, Wph, bp, d_out);
    proj<true ><<<BB, 128, 0, stream>>>(flag, Hfb, Wph, bp, d_out);
}

// Round 8
// 4589.714 us; speedup vs baseline: 5.2212x; 1.0340x over previous
//
#include <hip/hip_runtime.h>
#include <hip/hip_bf16.h>
#include <stdint.h>

#define HD   512   // hidden dim H
#define ID   128   // input dim I
#define NCLS 100   // num classes
#define TT   512   // sequence length T
#define BB   128   // batch B
#define NEMB 101   // NC + 1 embedding rows
#define NGRP 32    // independent batch groups
#define GWG  8     // workgroups per group (sync clique)
#define RPG  4     // batch rows per group
#define COLS 64    // hidden cols per WG (GWG*COLS == HD)
#define CPAD 520   // LDS C row stride (8-float pad: keeps 16B align, skews banks)

// workspace layout (bytes)
#define WS_FLAG 0
#define WS_BAR  1024                  // uint bars[NGRP*32] (128 B apart)
#define WS_G    16384                 // float G[101][2048]  (808 KB)
#define WS_C0   (1u * 1024 * 1024)    // float C0[128][512]  (256 KB)
#define WS_C1   (WS_C0 + 262144)      // float C1[128][512]  (256 KB)
#define WS_HFB  (WS_C1 + 262144)      // float Hfb[128][512] (256 KB)

using bf16 = __hip_bfloat16;

__device__ __forceinline__ float b2f(bf16 v) { return __bfloat162float(v); }
__device__ __forceinline__ float sigf(float x) { return 1.0f / (1.0f + expf(-x)); }

// coherent (IF-scope) C-state accessors: sc1 loads/stores bypass the
// non-coherent per-XCD L2 — no fences / cache-maintenance needed.
__device__ __forceinline__ float cld(const float* p) {
    return __hip_atomic_load(p, __ATOMIC_RELAXED, __HIP_MEMORY_SCOPE_AGENT);
}
__device__ __forceinline__ void cst(float* p, float v) {
    __hip_atomic_store(p, v, __ATOMIC_RELAXED, __HIP_MEMORY_SCOPE_AGENT);
}

template <bool BF>
__device__ __forceinline__ float ldv(const void* p, int i) {
    if constexpr (BF) return b2f(((const bf16*)p)[i]);
    else              return ((const float*)p)[i];
}

// ---------------------------------------------------------------------------
// Dtype sniffer + barrier zeroing. emb row 0 is exactly 0.0 by construction:
// bytes [256,512) are zero iff f32 (row 0) and nonzero iff bf16 (row 1).
// ---------------------------------------------------------------------------
__global__ void init_k(const uint32_t* __restrict__ emb_raw,
                       int* __restrict__ flag, unsigned int* __restrict__ bars) {
    const int t = threadIdx.x;
    if (t < NGRP * 32) bars[t] = 0u;
    if (t == 0) {
        uint32_t acc = 0;
        for (int i = 64; i < 128; ++i) acc |= emb_raw[i];
        *flag = (acc == 0u) ? 0 : 1;
    }
}

// ---------------------------------------------------------------------------
// G[c][j]: input-side gate pre-activations per class. j = q*512 + col,
// q in {0:f, 1:i, 2:o, 3:ctilde}; ctilde quarter pre-sigmoided.
// ---------------------------------------------------------------------------
template <bool BF>
__global__ void build_G(const int* __restrict__ flag,
                        const void* __restrict__ emb,
                        const void* __restrict__ Wfx, const void* __restrict__ Wix,
                        const void* __restrict__ Wox, const void* __restrict__ Wcx,
                        const void* __restrict__ bfv, const void* __restrict__ biv,
                        const void* __restrict__ bov, const void* __restrict__ bcv,
                        float* __restrict__ G) {
    if (*flag != (BF ? 1 : 0)) return;
    const int c   = blockIdx.x;
    const int j   = blockIdx.y * 256 + threadIdx.x;
    const int q   = j >> 9;
    const int col = j & 511;
    const void* W  = (q == 0) ? Wfx : (q == 1) ? Wix : (q == 2) ? Wox : Wcx;
    const void* bv = (q == 0) ? bfv : (q == 1) ? biv : (q == 2) ? bov : bcv;
    float acc = ldv<BF>(bv, col);
    for (int i = 0; i < ID; ++i)
        acc += ldv<BF>(emb, c * ID + i) * ldv<BF>(W, i * HD + col);
    if (q == 3) acc = sigf(acc);
    G[c * 2048 + j] = acc;
}

// ---------------------------------------------------------------------------
// Group-local barrier, fence-free (sc1 data path + relaxed agent atomics).
// __syncthreads drains each wave's sc1 C stores before the leader's add.
// ---------------------------------------------------------------------------
__device__ __forceinline__ void gbarrier(unsigned int* cnt, unsigned int* iter) {
    __syncthreads();
    if (threadIdx.x == 0) {
        __hip_atomic_fetch_add(cnt, 1u, __ATOMIC_RELAXED, __HIP_MEMORY_SCOPE_AGENT);
        const unsigned int tgt = (*iter + 1u) * GWG;
        while (__hip_atomic_load(cnt, __ATOMIC_RELAXED, __HIP_MEMORY_SCOPE_AGENT) < tgt)
            __builtin_amdgcn_s_sleep(1);
    }
    ++*iter;
    __syncthreads();
}

// ---------------------------------------------------------------------------
// Batch-split recurrence. Group g (8 WGs) owns rows 4g..4g+3; WG rank owns
// cols h0=64*rank..h0+63. Weights (f,i for 64 h' x own col) pinned in VGPRs
// (128 f32/thread). __launch_bounds__(512, 1): VGPR cap 512, NOT 128 —
// launch_bounds(512,2) capped at 128 and spilled the weight array to scratch
// (round-7 FETCH showed the 8 MB/step reload). ~190 VGPR also forces
// 1 WG/CU -> all 256 CUs active. Per step:
//   stage C(t) into LDS (4 coalesced sc1 loads/thread) -> sync
//   wave w: 16 ds_read_b128 of its h' segment x 4 rows + 512 reg-FMA
//   LDS partial reduce -> 256 update threads apply gates (own C elem in reg)
//   sc1-write 64-col slice -> group barrier.
// o-gate once at the end (h is dead state mid-sequence).
// ---------------------------------------------------------------------------
template <bool BF>
__global__ __launch_bounds__(512, 1) void recur_bs(
    const int* __restrict__ flag, const int* __restrict__ x,
    const float* __restrict__ G,
    const void* __restrict__ Wfc, const void* __restrict__ Wic,
    const void* __restrict__ Woc,
    float* __restrict__ C0, float* __restrict__ C1,
    float* __restrict__ Hfb, unsigned int* __restrict__ bars)
{
    if (*flag != (BF ? 1 : 0)) return;

    const int blk  = blockIdx.x;
    const int grp  = (blk & 7) * 4 + ((blk >> 3) >> 3);  // 0..31
    const int rank = (blk >> 3) & 7;                     // 0..7
    const int r0   = grp * RPG;
    const int h0   = rank * COLS;
    const int tid  = threadIdx.x;
    const int w    = tid >> 6;           // wave id = h' segment
    const int l    = tid & 63;           // lane = col within WG
    unsigned int* bar = bars + grp * 32; // 128 B apart

    __shared__ __align__(16) float Cs[RPG * CPAD];   // staged C(t), padded rows
    __shared__ float part[8][64][9];     // padded: stride 9 breaks bank conflicts
    __shared__ float dots[2 * COLS][RPG];
    __shared__ int   idx_s[RPG][TT];
    __shared__ int   lz[RPG];

    // ---- stage x rows, find group start step ----
    for (int r = 0; r < RPG; ++r)
        idx_s[r][tid] = x[(r0 + r) * TT + tid];
    if (tid < RPG) lz[tid] = -1;
    __syncthreads();
    for (int r = 0; r < RPG; ++r)
        if (idx_s[r][tid] == 0) atomicMax(&lz[r], tid);
    __syncthreads();
    const int t0 = min(min(lz[0], lz[1]), min(lz[2], lz[3])) + 1;

    // ---- persistent register weights, pinned so they can't rematerialize ----
    float wf[64], wi[64];
    #pragma unroll
    for (int k = 0; k < 64; ++k) {
        const int hp = w * 64 + k;
        wf[k] = ldv<BF>(Wfc, hp * HD + h0 + l);
        wi[k] = ldv<BF>(Wic, hp * HD + h0 + l);
    }
    #pragma unroll
    for (int k = 0; k < 64; ++k)
        asm volatile("" : "+v"(wf[k]), "+v"(wi[k]));

    // ---- zero our C slices in both buffers (coherent stores) ----
    if (tid < COLS * RPG) {
        const int c = tid & 63, r = tid >> 6;
        cst(&C0[(r0 + r) * HD + h0 + c], 0.0f);
        cst(&C1[(r0 + r) * HD + h0 + c], 0.0f);
    }
    unsigned int bi = 0;
    gbarrier(bar, &bi);                  // zeros visible group-wide

    float Creg = 0.0f;                   // update threads' own C element

    for (int t = t0; t < TT; ++t) {
        const float* cur = (t & 1) ? C1 : C0;
        float*       nxt = (t & 1) ? C0 : C1;

        // ---- stage C(t) into LDS: thread tid loads C[row j][h'=tid] ----
        {
            const float* cb = cur + r0 * HD + tid;
            float v0 = cld(cb);
            float v1 = cld(cb + HD);
            float v2 = cld(cb + 2 * HD);
            float v3 = cld(cb + 3 * HD);
            Cs[0 * CPAD + tid] = v0;
            Cs[1 * CPAD + tid] = v1;
            Cs[2 * CPAD + tid] = v2;
            Cs[3 * CPAD + tid] = v3;
        }
        __syncthreads();

        // ---- own-col partial dots over h' in [64w, 64w+64) ----
        float af0 = 0.f, af1 = 0.f, af2 = 0.f, af3 = 0.f;
        float ai0 = 0.f, ai1 = 0.f, ai2 = 0.f, ai3 = 0.f;
        {
            const float4* c4r0 = reinterpret_cast<const float4*>(Cs + 0 * CPAD + w * 64);
            const float4* c4r1 = reinterpret_cast<const float4*>(Cs + 1 * CPAD + w * 64);
            const float4* c4r2 = reinterpret_cast<const float4*>(Cs + 2 * CPAD + w * 64);
            const float4* c4r3 = reinterpret_cast<const float4*>(Cs + 3 * CPAD + w * 64);
            #pragma unroll
            for (int j = 0; j < 16; ++j) {
                const float4 c0v = c4r0[j];
                const float4 c1v = c4r1[j];
                const float4 c2v = c4r2[j];
                const float4 c3v = c4r3[j];
                const float w0 = wf[4 * j], w1 = wf[4 * j + 1], w2 = wf[4 * j + 2], w3 = wf[4 * j + 3];
                const float v0 = wi[4 * j], v1 = wi[4 * j + 1], v2 = wi[4 * j + 2], v3 = wi[4 * j + 3];
                af0 += w0 * c0v.x + w1 * c0v.y + w2 * c0v.z + w3 * c0v.w;
                af1 += w0 * c1v.x + w1 * c1v.y + w2 * c1v.z + w3 * c1v.w;
                af2 += w0 * c2v.x + w1 * c2v.y + w2 * c2v.z + w3 * c2v.w;
                af3 += w0 * c3v.x + w1 * c3v.y + w2 * c3v.z + w3 * c3v.w;
                ai0 += v0 * c0v.x + v1 * c0v.y + v2 * c0v.z + v3 * c0v.w;
                ai1 += v0 * c1v.x + v1 * c1v.y + v2 * c1v.z + v3 * c1v.w;
                ai2 += v0 * c2v.x + v1 * c2v.y + v2 * c2v.z + v3 * c2v.w;
                ai3 += v0 * c3v.x + v1 * c3v.y + v2 * c3v.z + v3 * c3v.w;
            }
        }
        part[w][l][0] = af0; part[w][l][1] = af1; part[w][l][2] = af2; part[w][l][3] = af3;
        part[w][l][4] = ai0; part[w][l][5] = ai1; part[w][l][6] = ai2; part[w][l][7] = ai3;
        __syncthreads();

        // reduce 8 h'-segments: thread t owns (cg = t&127, r = t>>7)
        {
            const int cg = tid & 127, rr = tid >> 7;
            const int sl = cg & 63, slot = (cg >> 6) * 4 + rr;
            float s = 0.0f;
            #pragma unroll
            for (int ww = 0; ww < 8; ++ww) s += part[ww][sl][slot];
            dots[cg][rr] = s;
        }
        __syncthreads();

        // update: thread t<256 owns (col c = t&63, row r = t>>6)
        if (tid < COLS * RPG) {
            const int c = tid & 63, r = tid >> 6;
            const int cl = idx_s[r][t];
            const float df = dots[c][r], di = dots[COLS + c][r];
            const float* Gr = G + cl * 2048;
            const float gf  = Gr[h0 + c];
            const float gi  = Gr[512 + h0 + c];
            const float sgc = Gr[1536 + h0 + c];
            float Cn = sgc * sigf(gi + di) + Creg * sigf(gf + df);
            Cn = (cl > 0) ? Cn : 0.0f;
            Creg = Cn;
            cst(&nxt[(r0 + r) * HD + h0 + c], Cn);
        }
        gbarrier(bar, &bi);
    }

    // ---- o-gate + h, once (TT even -> final C in C0) ----
    {
        const float* fin = C0;
        const float* cb = fin + r0 * HD + tid;
        float v0 = cld(cb);
        float v1 = cld(cb + HD);
        float v2 = cld(cb + 2 * HD);
        float v3 = cld(cb + 3 * HD);
        Cs[0 * CPAD + tid] = v0;
        Cs[1 * CPAD + tid] = v1;
        Cs[2 * CPAD + tid] = v2;
        Cs[3 * CPAD + tid] = v3;
        __syncthreads();

        float ao0 = 0.f, ao1 = 0.f, ao2 = 0.f, ao3 = 0.f;
        #pragma unroll 8
        for (int k = 0; k < 64; ++k) {
            const int hp = w * 64 + k;
            const float wo = ldv<BF>(Woc, hp * HD + h0 + l);
            ao0 += wo * Cs[0 * CPAD + hp];
            ao1 += wo * Cs[1 * CPAD + hp];
            ao2 += wo * Cs[2 * CPAD + hp];
            ao3 += wo * Cs[3 * CPAD + hp];
        }
        part[w][l][0] = ao0; part[w][l][1] = ao1; part[w][l][2] = ao2; part[w][l][3] = ao3;
        __syncthreads();
        if (tid < COLS * RPG) {
            const int c = tid & 63, r = tid >> 6;
            float s = 0.0f;
            #pragma unroll
            for (int ww = 0; ww < 8; ++ww) s += part[ww][c][r];
            const int cl = idx_s[r][TT - 1];
            const float o = sigf(G[cl * 2048 + 1024 + h0 + c] + s);
            Hfb[(r0 + r) * HD + h0 + c] = tanhf(Creg) * o;
        }
    }
}

// ---------------------------------------------------------------------------
// Projection + log_softmax, one WG per batch row.
// ---------------------------------------------------------------------------
template <bool BF>
__global__ __launch_bounds__(128) void proj(
    const int* __restrict__ flag, const float* __restrict__ Hfb,
    const void* __restrict__ Wph, const void* __restrict__ bp,
    void* __restrict__ out)
{
    if (*flag != (BF ? 1 : 0)) return;
    __shared__ __align__(16) float hv[HD];
    __shared__ float p_s[NCLS];
    __shared__ float lse_s;
    const int b   = blockIdx.x;
    const int tid = threadIdx.x;

    reinterpret_cast<float4*>(hv)[tid] =
        reinterpret_cast<const float4*>(Hfb + b * HD)[tid];
    __syncthreads();

    if (tid < NCLS) {
        float p = ldv<BF>(bp, tid);
        for (int h = 0; h < HD; ++h)
            p += hv[h] * ldv<BF>(Wph, h * NCLS + tid);
        p_s[tid] = p;
    }
    __syncthreads();
    if (tid == 0) {
        float m = -1e30f;
        for (int n = 0; n < NCLS; ++n) m = fmaxf(m, p_s[n]);
        float sum = 0.0f;
        for (int n = 0; n < NCLS; ++n) sum += expf(p_s[n] - m);
        lse_s = m + logf(sum);
    }
    __syncthreads();
    if (tid < NCLS) {
        const float v = p_s[tid] - lse_s;
        if constexpr (BF) ((bf16*)out)[b * NCLS + tid] = __float2bfloat16(v);
        else              ((float*)out)[b * NCLS + tid] = v;
    }
}

// ---------------------------------------------------------------------------
extern "C" void kernel_launch(void* const* d_in, const int* in_sizes, int n_in,
                              void* d_out, int out_size, void* d_ws, size_t ws_size,
                              hipStream_t stream) {
    const int*  x   = (const int*)d_in[0];
    const void* emb = d_in[1];
    const void* Wfx = d_in[2];
    const void* Wfc = d_in[3];
    const void* bfv = d_in[4];
    const void* Wix = d_in[5];
    const void* Wic = d_in[6];
    const void* biv = d_in[7];
    const void* Wox = d_in[8];
    const void* Woc = d_in[9];
    const void* bov = d_in[10];
    const void* Wcx = d_in[11];
    const void* bcv = d_in[12];
    const void* Wph = d_in[13];
    const void* bp  = d_in[14];

    int*          flag = (int*)((char*)d_ws + WS_FLAG);
    unsigned int* bars = (unsigned int*)((char*)d_ws + WS_BAR);
    float*        G    = (float*)((char*)d_ws + WS_G);
    float*        C0   = (float*)((char*)d_ws + WS_C0);
    float*        C1   = (float*)((char*)d_ws + WS_C1);
    float*        Hfb  = (float*)((char*)d_ws + WS_HFB);

    init_k<<<1, 1024, 0, stream>>>((const uint32_t*)emb, flag, bars);

    build_G<false><<<dim3(NEMB, 8), 256, 0, stream>>>(flag, emb, Wfx, Wix, Wox, Wcx,
                                                      bfv, biv, bov, bcv, G);
    build_G<true ><<<dim3(NEMB, 8), 256, 0, stream>>>(flag, emb, Wfx, Wix, Wox, Wcx,
                                                      bfv, biv, bov, bcv, G);

    {
        void* args[] = {(void*)&flag, (void*)&x, (void*)&G,
                        (void*)&Wfc, (void*)&Wic, (void*)&Woc,
                        (void*)&C0, (void*)&C1, (void*)&Hfb, (void*)&bars};
        hipLaunchCooperativeKernel((const void*)recur_bs<false>, dim3(NGRP * GWG), dim3(512),
                                   args, 0, stream);
        hipLaunchCooperativeKernel((const void*)recur_bs<true>, dim3(NGRP * GWG), dim3(512),
                                   args, 0, stream);
    }

    proj<false><<<BB, 128, 0, stream>>>(flag, Hfb, Wph, bp, d_out);
    proj<true ><<<BB, 128, 0, stream>>>(flag, Hfb, Wph, bp, d_out);
}